// Round 5
// baseline (2542.555 us; speedup 1.0000x reference)
//
#include <hip/hip_runtime.h>
#include <math.h>

#define TT  1024
#define DD  2048
#define NHH 2048
#define CC  1000

// ---------------------------------------------------------------------------
// GEMM: XH = x @ Wh^T ; XZ = x @ Wz^T + bz   (fp32, 64x64 tile, BK=32)
// grid (NHH/64, TT/64, 2); z=0 -> Wh/XH, z=1 -> Wz/XZ+bias
// ---------------------------------------------------------------------------
__global__ __launch_bounds__(256) void k_gemm(const float* __restrict__ X,
                                              const float* __restrict__ Wh,
                                              const float* __restrict__ Wz,
                                              const float* __restrict__ bz,
                                              float* __restrict__ XH,
                                              float* __restrict__ XZ) {
    __shared__ float As[32][68];   // [k][m]
    __shared__ float Bs[32][68];   // [k][n]
    const int z = blockIdx.z;
    const float* __restrict__ W = z ? Wz : Wh;
    float* __restrict__ OUT = z ? XZ : XH;
    const int n0 = blockIdx.x * 64;
    const int m0 = blockIdx.y * 64;
    const int tid = threadIdx.x;
    const int tx = tid & 15, ty = tid >> 4;
    const int lr = tid >> 2;           // 0..63 row within tile
    const int lc = (tid & 3) * 8;      // 0,8,16,24 col base

    float acc[4][4] = {};
    for (int k0 = 0; k0 < DD; k0 += 32) {
        float4 a0 = *(const float4*)&X[(size_t)(m0 + lr) * DD + k0 + lc];
        float4 a1 = *(const float4*)&X[(size_t)(m0 + lr) * DD + k0 + lc + 4];
        float4 b0 = *(const float4*)&W[(size_t)(n0 + lr) * DD + k0 + lc];
        float4 b1 = *(const float4*)&W[(size_t)(n0 + lr) * DD + k0 + lc + 4];
        As[lc+0][lr]=a0.x; As[lc+1][lr]=a0.y; As[lc+2][lr]=a0.z; As[lc+3][lr]=a0.w;
        As[lc+4][lr]=a1.x; As[lc+5][lr]=a1.y; As[lc+6][lr]=a1.z; As[lc+7][lr]=a1.w;
        Bs[lc+0][lr]=b0.x; Bs[lc+1][lr]=b0.y; Bs[lc+2][lr]=b0.z; Bs[lc+3][lr]=b0.w;
        Bs[lc+4][lr]=b1.x; Bs[lc+5][lr]=b1.y; Bs[lc+6][lr]=b1.z; Bs[lc+7][lr]=b1.w;
        __syncthreads();
#pragma unroll
        for (int kk = 0; kk < 32; ++kk) {
            float4 av = *(const float4*)&As[kk][ty * 4];
            float4 bv = *(const float4*)&Bs[kk][tx * 4];
            acc[0][0] = fmaf(av.x, bv.x, acc[0][0]); acc[0][1] = fmaf(av.x, bv.y, acc[0][1]);
            acc[0][2] = fmaf(av.x, bv.z, acc[0][2]); acc[0][3] = fmaf(av.x, bv.w, acc[0][3]);
            acc[1][0] = fmaf(av.y, bv.x, acc[1][0]); acc[1][1] = fmaf(av.y, bv.y, acc[1][1]);
            acc[1][2] = fmaf(av.y, bv.z, acc[1][2]); acc[1][3] = fmaf(av.y, bv.w, acc[1][3]);
            acc[2][0] = fmaf(av.z, bv.x, acc[2][0]); acc[2][1] = fmaf(av.z, bv.y, acc[2][1]);
            acc[2][2] = fmaf(av.z, bv.z, acc[2][2]); acc[2][3] = fmaf(av.z, bv.w, acc[2][3]);
            acc[3][0] = fmaf(av.w, bv.x, acc[3][0]); acc[3][1] = fmaf(av.w, bv.y, acc[3][1]);
            acc[3][2] = fmaf(av.w, bv.z, acc[3][2]); acc[3][3] = fmaf(av.w, bv.w, acc[3][3]);
        }
        __syncthreads();
    }
    float4 bias = make_float4(0.f, 0.f, 0.f, 0.f);
    if (z) bias = *(const float4*)&bz[n0 + tx * 4];
#pragma unroll
    for (int i = 0; i < 4; ++i) {
        float4 o = make_float4(acc[i][0] + bias.x, acc[i][1] + bias.y,
                               acc[i][2] + bias.z, acc[i][3] + bias.w);
        *(float4*)&OUT[(size_t)(m0 + ty * 4 + i) * NHH + n0 + tx * 4] = o;
    }
}

// ---------------------------------------------------------------------------
// Recurrent scan, 1 timestep per round, VALIDATE-AT-USE schedule.
// Model from rounds 0-4: R = span^-1 * (L_vis + C); baseline validated one
// phase after publishing (span~1) -> R ~ L_vis ~ 1.7us. Epoch t+1 (published
// round t) is only USED by round t+2's matvec, so validation belongs at
// round t+2's HEAD, giving span~2 -> R ~ (L_vis+C)/2 ~ 1.0-1.2us.
// Round t (t=1..1023):
//   1. spin-validate epoch t-1 (gather loads issued at end of round t-1),
//      write Hs[t&1], ONE __syncthreads              [skipped for t=1,2:
//      P_0 AND P_1 are locally computable elementwise by every WG]
//   2. matvec U@P_{t-1} (U rows in VGPRs, 2 Uz + 2 Uh per wave)
//   3. 64-lane butterfly; lanes 0/1 hold (dz,dh) -> gates, advance own
//      element, publish epoch t+1 (packed Hbuf, relaxed AGENT scope —
//      round-3 lesson: system scope writes through to HBM, +0.3us)
//   4. issue gather loads for epoch t (validated at round t+1 head)
// 256 WGs x 256 thr, 1 WG/CU (round-2 lesson: per-CU path is sacred).
// Safety: writer lead <= 2 epochs < slot distance 4. Overwriting slot s
// (epoch t+1, round t) is preceded by validating epoch t-1, which implies
// every WG published t-1 (round t-2), which is program-order after their
// reads of epoch t-3 — the previous occupant of slot s. Tag monotone
// 1..1024, single u64 tag+value -> no torn reads, no cross-run ABA.
// ---------------------------------------------------------------------------
__global__ __launch_bounds__(256, 1) void k_recur(
    const float* __restrict__ XH, const float* __restrict__ XZ,
    const float* __restrict__ Uh, const float* __restrict__ Uz,
    const float* __restrict__ zt0, const float* __restrict__ ht0,
    const float* __restrict__ hp0,
    unsigned long long* __restrict__ Hbuf) {
    __shared__ float Hs[2][NHH];
    const int tid  = threadIdx.x;
    const int wave = tid >> 6, lane = tid & 63;
    const int base8 = blockIdx.x * 8;
    const int e0 = base8 + 2 * wave;       // this wave's 2 elements: e0, e0+1

    // U rows in registers: u[0..1] = Uz rows e0,e0+1 ; u[2..3] = Uh rows
    float u[4][32];
#pragma unroll
    for (int r = 0; r < 2; ++r) {
        const float* __restrict__ rowz = Uz + (size_t)(e0 + r) * NHH;
        const float* __restrict__ rowh = Uh + (size_t)(e0 + r) * NHH;
#pragma unroll
        for (int c = 0; c < 8; ++c) {
            float4 vz = *(const float4*)&rowz[c * 256 + lane * 4];
            float4 vh = *(const float4*)&rowh[c * 256 + lane * 4];
            u[r][c*4+0]=vz.x; u[r][c*4+1]=vz.y; u[r][c*4+2]=vz.z; u[r][c*4+3]=vz.w;
            u[2+r][c*4+0]=vh.x; u[2+r][c*4+1]=vh.y; u[2+r][c*4+2]=vh.z; u[2+r][c*4+3]=vh.w;
        }
    }

    // prologue: Hs[1] = P_0 (round 1's operand), Hs[0] = P_1 (round 2's) —
    // both elementwise-computable locally, no communication.
#pragma unroll
    for (int k = 0; k < 8; ++k) {
        const int i = k * 256 + tid;
        float p0 = hp0[i], z0 = zt0[i], g0 = ht0[i];
        Hs[1][i] = p0;
        Hs[0][i] = (1.0f - z0) * p0 + z0 * g0;
    }
    float p_cur = 0.f;                     // own element of P_1
    if (lane < 2) {
        const int e = e0 + lane;
        p_cur = (1.0f - zt0[e]) * hp0[e] + zt0[e] * ht0[e];
    }
    float xz_n = 0.f, xh_n = 0.f;          // x-projections for round 1 (row 0)
    if (lane < 2) {
        xz_n = XZ[e0 + lane];
        xh_n = XH[e0 + lane];
    }
    __syncthreads();

    unsigned long long pv[8];
    for (int t = 1; t < TT; ++t) {
        // 1. validate epoch t-1 (published round t-2, loads issued round t-1)
        if (t >= 3) {
            const unsigned long long* __restrict__ src =
                Hbuf + (size_t)((t - 1) & 3) * NHH;
            for (;;) {
                unsigned stale = 0;
#pragma unroll
                for (int k = 0; k < 8; ++k)
                    if ((unsigned)(pv[k] >> 32) != (unsigned)(t - 1)) stale |= (1u << k);
                if (!stale) break;
#pragma unroll
                for (int k = 0; k < 8; ++k)
                    if (stale & (1u << k))
                        pv[k] = __hip_atomic_load(&src[k * 256 + tid],
                                                  __ATOMIC_RELAXED, __HIP_MEMORY_SCOPE_AGENT);
            }
#pragma unroll
            for (int k = 0; k < 8; ++k)
                Hs[t & 1][k * 256 + tid] = __uint_as_float((unsigned)pv[k]);
            __syncthreads();
        }

        const float xzv = xz_n, xhv = xh_n;
        if (lane < 2 && t < TT - 1) {      // prefetch next round's row t
            xz_n = XZ[(size_t)t * NHH + e0 + lane];
            xh_n = XH[(size_t)t * NHH + e0 + lane];
        }

        // 2. matvec on Hs[t&1] = P_{t-1}: 2 Uz rows + 2 Uh rows, U in VGPRs
        const float* __restrict__ H = Hs[t & 1];
        float a0 = 0.f, a1 = 0.f, a2 = 0.f, a3 = 0.f;
#pragma unroll
        for (int c = 0; c < 8; ++c) {
            float4 h4 = *(const float4*)&H[c * 256 + lane * 4];
            a0 = fmaf(u[0][c*4+0], h4.x, fmaf(u[0][c*4+1], h4.y, fmaf(u[0][c*4+2], h4.z, fmaf(u[0][c*4+3], h4.w, a0))));
            a1 = fmaf(u[1][c*4+0], h4.x, fmaf(u[1][c*4+1], h4.y, fmaf(u[1][c*4+2], h4.z, fmaf(u[1][c*4+3], h4.w, a1))));
            a2 = fmaf(u[2][c*4+0], h4.x, fmaf(u[2][c*4+1], h4.y, fmaf(u[2][c*4+2], h4.z, fmaf(u[2][c*4+3], h4.w, a2))));
            a3 = fmaf(u[3][c*4+0], h4.x, fmaf(u[3][c*4+1], h4.y, fmaf(u[3][c*4+2], h4.z, fmaf(u[3][c*4+3], h4.w, a3))));
        }
#pragma unroll
        for (int off = 32; off > 0; off >>= 1) {
            a0 += __shfl_xor(a0, off); a1 += __shfl_xor(a1, off);
            a2 += __shfl_xor(a2, off); a3 += __shfl_xor(a3, off);
        }

        // 3. gates + publish epoch t+1 (per-wave; butterfly filled all lanes)
        if (lane < 2) {
            float dz = lane ? a1 : a0;
            float dh = lane ? a3 : a2;
            float z = 1.0f / (1.0f + expf(-(xzv + dz)));
            float g = tanhf(xhv + dh);
            float pn = (1.0f - z) * p_cur + z * g;
            p_cur = pn;
            __hip_atomic_store(&Hbuf[(size_t)((t + 1) & 3) * NHH + e0 + lane],
                ((unsigned long long)(unsigned)(t + 1) << 32)
                    | (unsigned long long)__float_as_uint(pn),
                __ATOMIC_RELAXED, __HIP_MEMORY_SCOPE_AGENT);
        }
        if (t == TT - 1) break;            // epoch 1024 published; done

        // 4. issue gather loads for epoch t (validated at round t+1 head)
        if (t >= 2) {
            const unsigned long long* __restrict__ s2 =
                Hbuf + (size_t)(t & 3) * NHH;
#pragma unroll
            for (int k = 0; k < 8; ++k)
                pv[k] = __hip_atomic_load(&s2[k * 256 + tid],
                                          __ATOMIC_RELAXED, __HIP_MEMORY_SCOPE_AGENT);
        }
        // rounds 1-2 have no head-barrier; separate round 1's Hs[1] reads
        // from round 3's Hs[1] writes
        if (t == 2) __syncthreads();
    }
}

// ---------------------------------------------------------------------------
// logits[r] = Wout[r,:] . P_1024   (epoch 1024 -> slot 0, value in low bits)
// ---------------------------------------------------------------------------
__global__ __launch_bounds__(256) void k_logits(const unsigned long long* __restrict__ Hbuf,
                                                const float* __restrict__ Wout,
                                                float* __restrict__ lg) {
    __shared__ float Hs[NHH];
    const int tid = threadIdx.x;
    for (int k = tid; k < NHH; k += 256) Hs[k] = __uint_as_float((unsigned)Hbuf[k]);
    __syncthreads();
    const int wave = tid >> 6, lane = tid & 63;
    const int row = blockIdx.x * 4 + wave;
    float a = 0.f;
#pragma unroll
    for (int c = 0; c < 8; ++c) {
        float4 w = *(const float4*)&Wout[(size_t)row * NHH + c * 256 + lane * 4];
        float4 h = *(const float4*)&Hs[c * 256 + lane * 4];
        a = fmaf(w.x, h.x, fmaf(w.y, h.y, fmaf(w.z, h.z, fmaf(w.w, h.w, a))));
    }
#pragma unroll
    for (int off = 32; off > 0; off >>= 1) a += __shfl_xor(a, off);
    if (lane == 0) lg[row] = a;
}

// ---------------------------------------------------------------------------
// softmax over 1000 logits, single block
// ---------------------------------------------------------------------------
__global__ __launch_bounds__(1024) void k_softmax(const float* __restrict__ lg,
                                                  float* __restrict__ out) {
    const int i = threadIdx.x;
    __shared__ float red[16];
    __shared__ float bc[2];
    float v = (i < CC) ? lg[i] : -3.0e38f;
    float m = v;
#pragma unroll
    for (int off = 32; off > 0; off >>= 1) m = fmaxf(m, __shfl_xor(m, off));
    if ((i & 63) == 0) red[i >> 6] = m;
    __syncthreads();
    if (i == 0) { float mm = red[0]; for (int k = 1; k < 16; ++k) mm = fmaxf(mm, red[k]); bc[0] = mm; }
    __syncthreads();
    float e = (i < CC) ? expf(v - bc[0]) : 0.f;
    float s = e;
#pragma unroll
    for (int off = 32; off > 0; off >>= 1) s += __shfl_xor(s, off);
    if ((i & 63) == 0) red[i >> 6] = s;
    __syncthreads();
    if (i == 0) { float ss = 0.f; for (int k = 0; k < 16; ++k) ss += red[k]; bc[1] = ss; }
    __syncthreads();
    if (i < CC) out[i] = e / bc[1];
}

extern "C" void kernel_launch(void* const* d_in, const int* in_sizes, int n_in,
                              void* d_out, int out_size, void* d_ws, size_t ws_size,
                              hipStream_t stream) {
    const float* x    = (const float*)d_in[0];
    const float* Wh   = (const float*)d_in[1];
    const float* Wz   = (const float*)d_in[2];
    // d_in[3] = Wr  (dead code in reference)
    const float* Uh   = (const float*)d_in[4];
    const float* Uz   = (const float*)d_in[5];
    const float* bz   = (const float*)d_in[6];
    // d_in[7] = Ur, d_in[8] = br (dead code)
    const float* Wout = (const float*)d_in[9];
    // d_in[10] = h0 (overwritten before first use since T>=1)
    const float* zt0  = (const float*)d_in[11];
    const float* ht0  = (const float*)d_in[12];
    const float* hp0  = (const float*)d_in[13];
    float* out = (float*)d_out;

    float* XH = (float*)d_ws;                                   // T*NH f32
    float* XZ = XH + (size_t)TT * NHH;                          // T*NH f32
    unsigned long long* Hbuf = (unsigned long long*)(XZ + (size_t)TT * NHH); // 4*NH u64
    float* lg = (float*)(Hbuf + 4 * NHH);                       // CC f32

    k_gemm<<<dim3(NHH / 64, TT / 64, 2), dim3(256), 0, stream>>>(x, Wh, Wz, bz, XH, XZ);
    k_recur<<<dim3(256), dim3(256), 0, stream>>>(XH, XZ, Uh, Uz, zt0, ht0, hp0, Hbuf);
    k_logits<<<dim3(250), dim3(256), 0, stream>>>(Hbuf, Wout, lg);
    k_softmax<<<dim3(1), dim3(1024), 0, stream>>>(lg, out);
}

// Round 6
// 2036.713 us; speedup vs baseline: 1.2484x; 1.2484x over previous
//
#include <hip/hip_runtime.h>
#include <math.h>

#define TT  1024
#define DD  2048
#define NHH 2048
#define CC  1000

// ---------------------------------------------------------------------------
// GEMM: XH = x @ Wh^T ; XZ = x @ Wz^T + bz   (fp32, 64x64 tile, BK=32)
// grid (NHH/64, TT/64, 2); z=0 -> Wh/XH, z=1 -> Wz/XZ+bias
// ---------------------------------------------------------------------------
__global__ __launch_bounds__(256) void k_gemm(const float* __restrict__ X,
                                              const float* __restrict__ Wh,
                                              const float* __restrict__ Wz,
                                              const float* __restrict__ bz,
                                              float* __restrict__ XH,
                                              float* __restrict__ XZ) {
    __shared__ float As[32][68];   // [k][m]
    __shared__ float Bs[32][68];   // [k][n]
    const int z = blockIdx.z;
    const float* __restrict__ W = z ? Wz : Wh;
    float* __restrict__ OUT = z ? XZ : XH;
    const int n0 = blockIdx.x * 64;
    const int m0 = blockIdx.y * 64;
    const int tid = threadIdx.x;
    const int tx = tid & 15, ty = tid >> 4;
    const int lr = tid >> 2;           // 0..63 row within tile
    const int lc = (tid & 3) * 8;      // 0,8,16,24 col base

    float acc[4][4] = {};
    for (int k0 = 0; k0 < DD; k0 += 32) {
        float4 a0 = *(const float4*)&X[(size_t)(m0 + lr) * DD + k0 + lc];
        float4 a1 = *(const float4*)&X[(size_t)(m0 + lr) * DD + k0 + lc + 4];
        float4 b0 = *(const float4*)&W[(size_t)(n0 + lr) * DD + k0 + lc];
        float4 b1 = *(const float4*)&W[(size_t)(n0 + lr) * DD + k0 + lc + 4];
        As[lc+0][lr]=a0.x; As[lc+1][lr]=a0.y; As[lc+2][lr]=a0.z; As[lc+3][lr]=a0.w;
        As[lc+4][lr]=a1.x; As[lc+5][lr]=a1.y; As[lc+6][lr]=a1.z; As[lc+7][lr]=a1.w;
        Bs[lc+0][lr]=b0.x; Bs[lc+1][lr]=b0.y; Bs[lc+2][lr]=b0.z; Bs[lc+3][lr]=b0.w;
        Bs[lc+4][lr]=b1.x; Bs[lc+5][lr]=b1.y; Bs[lc+6][lr]=b1.z; Bs[lc+7][lr]=b1.w;
        __syncthreads();
#pragma unroll
        for (int kk = 0; kk < 32; ++kk) {
            float4 av = *(const float4*)&As[kk][ty * 4];
            float4 bv = *(const float4*)&Bs[kk][tx * 4];
            acc[0][0] = fmaf(av.x, bv.x, acc[0][0]); acc[0][1] = fmaf(av.x, bv.y, acc[0][1]);
            acc[0][2] = fmaf(av.x, bv.z, acc[0][2]); acc[0][3] = fmaf(av.x, bv.w, acc[0][3]);
            acc[1][0] = fmaf(av.y, bv.x, acc[1][0]); acc[1][1] = fmaf(av.y, bv.y, acc[1][1]);
            acc[1][2] = fmaf(av.y, bv.z, acc[1][2]); acc[1][3] = fmaf(av.y, bv.w, acc[1][3]);
            acc[2][0] = fmaf(av.z, bv.x, acc[2][0]); acc[2][1] = fmaf(av.z, bv.y, acc[2][1]);
            acc[2][2] = fmaf(av.z, bv.z, acc[2][2]); acc[2][3] = fmaf(av.z, bv.w, acc[2][3]);
            acc[3][0] = fmaf(av.w, bv.x, acc[3][0]); acc[3][1] = fmaf(av.w, bv.y, acc[3][1]);
            acc[3][2] = fmaf(av.w, bv.z, acc[3][2]); acc[3][3] = fmaf(av.w, bv.w, acc[3][3]);
        }
        __syncthreads();
    }
    float4 bias = make_float4(0.f, 0.f, 0.f, 0.f);
    if (z) bias = *(const float4*)&bz[n0 + tx * 4];
#pragma unroll
    for (int i = 0; i < 4; ++i) {
        float4 o = make_float4(acc[i][0] + bias.x, acc[i][1] + bias.y,
                               acc[i][2] + bias.z, acc[i][3] + bias.w);
        *(float4*)&OUT[(size_t)(m0 + ty * 4 + i) * NHH + n0 + tx * 4] = o;
    }
}

// ---------------------------------------------------------------------------
// Recurrent scan — EXACT r0 structure (the proven 1.70us/round schedule:
// issue gathers early, matvec, dot_s, gates+publish, validate-at-tail),
// with ONE variable changed: all Hbuf atomics are SYSTEM scope.
// Evidence through round 5:
//  * schedule variants (pair rounds, head-validate span-2, fewer WGs,
//    single-writer lines) all regressed -> the floor is NOT store age or
//    line ownership; FETCH_SIZE ~121KB/round = 128 lines x 8 XCDs shows
//    polls hit the reader's XCD L2 and return CACHED STALE lines until
//    invalidation propagates (~1.3us) — the poll path is the bottleneck.
//  * r3 (system store + agent poll) proved store-side-only is useless.
// This round: system store + SYSTEM POLL — loads bypass L1+L2 and read the
// memory-side cache (MALL) directly; both sides meet at the coherence
// point, eliminating the stale-L2 window. Gathers are issued a full round
// after publish, so the value is already at the MALL when first polled.
// Protocol unchanged: 4-slot tagged (epoch<<32|f32bits) u64 exchange,
// relaxed ordering (self-validating tags tolerate any reordering),
// overwrite distance 4 > pipeline depth 2, tags monotone 1..1024.
// 256 WGs x 256 thr, 1 WG/CU; U rows register-resident (128 f32/lane).
// ---------------------------------------------------------------------------
__global__ __launch_bounds__(256, 1) void k_recur(
    const float* __restrict__ XH, const float* __restrict__ XZ,
    const float* __restrict__ Uh, const float* __restrict__ Uz,
    const float* __restrict__ zt0, const float* __restrict__ ht0,
    const float* __restrict__ hp0,
    unsigned long long* __restrict__ Hbuf) {
    __shared__ float Hs[NHH];
    __shared__ float dot_s[16];
    const int tid  = threadIdx.x;
    const int wave = tid >> 6, lane = tid & 63;
    const int base8 = blockIdx.x * 8;

    // load this wave's 4 U rows into registers
    const float* __restrict__ Um = (wave < 2) ? Uz : Uh;
    const int r0 = base8 + (wave & 1) * 4;
    float u[4][32];
#pragma unroll
    for (int r = 0; r < 4; ++r) {
        const float* __restrict__ row = Um + (size_t)(r0 + r) * NHH;
#pragma unroll
        for (int c = 0; c < 8; ++c) {
            float4 v = *(const float4*)&row[c * 256 + lane * 4];
            u[r][c*4+0] = v.x; u[r][c*4+1] = v.y; u[r][c*4+2] = v.z; u[r][c*4+3] = v.w;
        }
    }
    // Hs = P_0 = hprev0 (plain input, no tags needed for epoch 0)
#pragma unroll
    for (int k = 0; k < 8; ++k) Hs[k * 256 + tid] = hp0[k * 256 + tid];

    // own P_1 from initial gates; publish epoch 1
    float p_cur = 0.f;
    if (tid < 8) {
        float z0 = zt0[base8 + tid], g0 = ht0[base8 + tid], p0 = hp0[base8 + tid];
        p_cur = (1.0f - z0) * p0 + z0 * g0;
        unsigned long long pr = (1ull << 32) | (unsigned long long)__float_as_uint(p_cur);
        __hip_atomic_store(&Hbuf[(size_t)1 * NHH + base8 + tid], pr,
                           __ATOMIC_RELAXED, __HIP_MEMORY_SCOPE_SYSTEM);
    }
    __syncthreads();

    for (int t = 1; t < TT; ++t) {
        // (i) issue loads for epoch t; results not touched until (iv)
        const unsigned long long* __restrict__ src = Hbuf + (size_t)(t & 3) * NHH;
        unsigned long long pv[8];
#pragma unroll
        for (int k = 0; k < 8; ++k)
            pv[k] = __hip_atomic_load(&src[k * 256 + tid], __ATOMIC_RELAXED, __HIP_MEMORY_SCOPE_SYSTEM);
        float xzv = 0.f, xhv = 0.f;
        if (tid < 8) {
            xzv = XZ[(size_t)(t - 1) * NHH + base8 + tid];
            xhv = XH[(size_t)(t - 1) * NHH + base8 + tid];
        }
        // (ii) matvec: U @ P_{t-1} from LDS, 4 rows/wave, U in registers
        float a0 = 0.f, a1 = 0.f, a2 = 0.f, a3 = 0.f;
#pragma unroll
        for (int c = 0; c < 8; ++c) {
            float4 h4 = *(const float4*)&Hs[c * 256 + lane * 4];
            a0 = fmaf(u[0][c*4+0], h4.x, fmaf(u[0][c*4+1], h4.y, fmaf(u[0][c*4+2], h4.z, fmaf(u[0][c*4+3], h4.w, a0))));
            a1 = fmaf(u[1][c*4+0], h4.x, fmaf(u[1][c*4+1], h4.y, fmaf(u[1][c*4+2], h4.z, fmaf(u[1][c*4+3], h4.w, a1))));
            a2 = fmaf(u[2][c*4+0], h4.x, fmaf(u[2][c*4+1], h4.y, fmaf(u[2][c*4+2], h4.z, fmaf(u[2][c*4+3], h4.w, a2))));
            a3 = fmaf(u[3][c*4+0], h4.x, fmaf(u[3][c*4+1], h4.y, fmaf(u[3][c*4+2], h4.z, fmaf(u[3][c*4+3], h4.w, a3))));
        }
#pragma unroll
        for (int off = 32; off > 0; off >>= 1) {
            a0 += __shfl_xor(a0, off);
            a1 += __shfl_xor(a1, off);
            a2 += __shfl_xor(a2, off);
            a3 += __shfl_xor(a3, off);
        }
        if (lane == 0) {
            int di = ((wave & 1) * 4) + ((wave >> 1) * 8); // Uz -> 0..7, Uh -> 8..15
            dot_s[di + 0] = a0; dot_s[di + 1] = a1; dot_s[di + 2] = a2; dot_s[di + 3] = a3;
        }
        __syncthreads();
        // (iii) gates from P_{t-1} dots; P_{t+1} = (1-z)*P_t + z*g; publish
        if (tid < 8) {
            float z = 1.0f / (1.0f + expf(-(xzv + dot_s[tid])));
            float g = tanhf(xhv + dot_s[8 + tid]);
            float pn = (1.0f - z) * p_cur + z * g;
            p_cur = pn;
            unsigned long long pr = ((unsigned long long)(unsigned)(t + 1) << 32)
                                  | (unsigned long long)__float_as_uint(pn);
            __hip_atomic_store(&Hbuf[(size_t)((t + 1) & 3) * NHH + base8 + tid], pr,
                               __ATOMIC_RELAXED, __HIP_MEMORY_SCOPE_SYSTEM);
        }
        // (iv) validate epoch-t tags; batched parallel retry of stale ones
        for (;;) {
            unsigned stale = 0;
#pragma unroll
            for (int k = 0; k < 8; ++k)
                if ((unsigned)(pv[k] >> 32) != (unsigned)t) stale |= (1u << k);
            if (!stale) break;
#pragma unroll
            for (int k = 0; k < 8; ++k)
                if (stale & (1u << k))
                    pv[k] = __hip_atomic_load(&src[k * 256 + tid], __ATOMIC_RELAXED, __HIP_MEMORY_SCOPE_SYSTEM);
        }
#pragma unroll
        for (int k = 0; k < 8; ++k) Hs[k * 256 + tid] = __uint_as_float((unsigned)pv[k]);
        __syncthreads();
    }
}

// ---------------------------------------------------------------------------
// logits[r] = Wout[r,:] . P_1024   (epoch 1024 -> slot 0, value in low bits)
// ---------------------------------------------------------------------------
__global__ __launch_bounds__(256) void k_logits(const unsigned long long* __restrict__ Hbuf,
                                                const float* __restrict__ Wout,
                                                float* __restrict__ lg) {
    __shared__ float Hs[NHH];
    const int tid = threadIdx.x;
    for (int k = tid; k < NHH; k += 256) Hs[k] = __uint_as_float((unsigned)Hbuf[k]);
    __syncthreads();
    const int wave = tid >> 6, lane = tid & 63;
    const int row = blockIdx.x * 4 + wave;
    float a = 0.f;
#pragma unroll
    for (int c = 0; c < 8; ++c) {
        float4 w = *(const float4*)&Wout[(size_t)row * NHH + c * 256 + lane * 4];
        float4 h = *(const float4*)&Hs[c * 256 + lane * 4];
        a = fmaf(w.x, h.x, fmaf(w.y, h.y, fmaf(w.z, h.z, fmaf(w.w, h.w, a))));
    }
#pragma unroll
    for (int off = 32; off > 0; off >>= 1) a += __shfl_xor(a, off);
    if (lane == 0) lg[row] = a;
}

// ---------------------------------------------------------------------------
// softmax over 1000 logits, single block
// ---------------------------------------------------------------------------
__global__ __launch_bounds__(1024) void k_softmax(const float* __restrict__ lg,
                                                  float* __restrict__ out) {
    const int i = threadIdx.x;
    __shared__ float red[16];
    __shared__ float bc[2];
    float v = (i < CC) ? lg[i] : -3.0e38f;
    float m = v;
#pragma unroll
    for (int off = 32; off > 0; off >>= 1) m = fmaxf(m, __shfl_xor(m, off));
    if ((i & 63) == 0) red[i >> 6] = m;
    __syncthreads();
    if (i == 0) { float mm = red[0]; for (int k = 1; k < 16; ++k) mm = fmaxf(mm, red[k]); bc[0] = mm; }
    __syncthreads();
    float e = (i < CC) ? expf(v - bc[0]) : 0.f;
    float s = e;
#pragma unroll
    for (int off = 32; off > 0; off >>= 1) s += __shfl_xor(s, off);
    if ((i & 63) == 0) red[i >> 6] = s;
    __syncthreads();
    if (i == 0) { float ss = 0.f; for (int k = 0; k < 16; ++k) ss += red[k]; bc[1] = ss; }
    __syncthreads();
    if (i < CC) out[i] = e / bc[1];
}

extern "C" void kernel_launch(void* const* d_in, const int* in_sizes, int n_in,
                              void* d_out, int out_size, void* d_ws, size_t ws_size,
                              hipStream_t stream) {
    const float* x    = (const float*)d_in[0];
    const float* Wh   = (const float*)d_in[1];
    const float* Wz   = (const float*)d_in[2];
    // d_in[3] = Wr  (dead code in reference)
    const float* Uh   = (const float*)d_in[4];
    const float* Uz   = (const float*)d_in[5];
    const float* bz   = (const float*)d_in[6];
    // d_in[7] = Ur, d_in[8] = br (dead code)
    const float* Wout = (const float*)d_in[9];
    // d_in[10] = h0 (overwritten before first use since T>=1)
    const float* zt0  = (const float*)d_in[11];
    const float* ht0  = (const float*)d_in[12];
    const float* hp0  = (const float*)d_in[13];
    float* out = (float*)d_out;

    float* XH = (float*)d_ws;                                   // T*NH f32
    float* XZ = XH + (size_t)TT * NHH;                          // T*NH f32
    unsigned long long* Hbuf = (unsigned long long*)(XZ + (size_t)TT * NHH); // 4*NH u64
    float* lg = (float*)(Hbuf + 4 * NHH);                       // CC f32

    k_gemm<<<dim3(NHH / 64, TT / 64, 2), dim3(256), 0, stream>>>(x, Wh, Wz, bz, XH, XZ);
    k_recur<<<dim3(256), dim3(256), 0, stream>>>(XH, XZ, Uh, Uz, zt0, ht0, hp0, Hbuf);
    k_logits<<<dim3(250), dim3(256), 0, stream>>>(Hbuf, Wout, lg);
    k_softmax<<<dim3(1), dim3(1024), 0, stream>>>(lg, out);
}

// Round 7
// 2033.781 us; speedup vs baseline: 1.2502x; 1.0014x over previous
//
#include <hip/hip_runtime.h>
#include <math.h>

#define TT  1024
#define DD  2048
#define NHH 2048
#define CC  1000

// ---------------------------------------------------------------------------
// GEMM: XH = x @ Wh^T ; XZ = x @ Wz^T + bz   (fp32)
// 128x128 tile, BK=32, 256 threads, 8x8 micro-tile, register-prefetch dbuf.
// grid (NHH/128, TT/128, 2) = 256 blocks = exactly 1/CU.
// Same sequential k-accumulation order as the previous 64x64 kernel ->
// bit-identical output. Halves redundant operand traffic (X read 16x not
// 32x, W 8x not 16x), 64 FMA per 4 LDS reads, 64 staging rounds/block.
// ---------------------------------------------------------------------------
__global__ __launch_bounds__(256) void k_gemm(const float* __restrict__ X,
                                              const float* __restrict__ Wh,
                                              const float* __restrict__ Wz,
                                              const float* __restrict__ bz,
                                              float* __restrict__ XH,
                                              float* __restrict__ XZ) {
    __shared__ float As[32][132];   // [k][m], +4 pad
    __shared__ float Bs[32][132];   // [k][n]
    const int z = blockIdx.z;
    const float* __restrict__ W = z ? Wz : Wh;
    float* __restrict__ OUT = z ? XZ : XH;
    const int n0 = blockIdx.x * 128;
    const int m0 = blockIdx.y * 128;
    const int tid = threadIdx.x;
    const int tx = tid & 15, ty = tid >> 4;   // 16x16 thread grid, 8x8 micro
    const int lr = tid >> 1;                  // staging row 0..127
    const int lq = (tid & 1) * 16;            // staging col base 0 / 16

    float4 pa[4], pb[4];
#pragma unroll
    for (int q = 0; q < 4; ++q) {             // prologue: tile 0 -> regs
        pa[q] = *(const float4*)&X[(size_t)(m0 + lr) * DD + lq + q * 4];
        pb[q] = *(const float4*)&W[(size_t)(n0 + lr) * DD + lq + q * 4];
    }
    float acc[8][8] = {};
    for (int k0 = 0; k0 < DD; k0 += 32) {
        // staged regs -> LDS (transposed to [k][m])
#pragma unroll
        for (int q = 0; q < 4; ++q) {
            const int kc = lq + q * 4;
            As[kc+0][lr]=pa[q].x; As[kc+1][lr]=pa[q].y; As[kc+2][lr]=pa[q].z; As[kc+3][lr]=pa[q].w;
            Bs[kc+0][lr]=pb[q].x; Bs[kc+1][lr]=pb[q].y; Bs[kc+2][lr]=pb[q].z; Bs[kc+3][lr]=pb[q].w;
        }
        __syncthreads();
        if (k0 + 32 < DD) {                   // prefetch next tile into regs
#pragma unroll
            for (int q = 0; q < 4; ++q) {
                pa[q] = *(const float4*)&X[(size_t)(m0 + lr) * DD + k0 + 32 + lq + q * 4];
                pb[q] = *(const float4*)&W[(size_t)(n0 + lr) * DD + k0 + 32 + lq + q * 4];
            }
        }
#pragma unroll
        for (int kk = 0; kk < 32; ++kk) {
            float4 a0 = *(const float4*)&As[kk][ty * 8];
            float4 a1 = *(const float4*)&As[kk][ty * 8 + 4];
            float4 b0 = *(const float4*)&Bs[kk][tx * 8];
            float4 b1 = *(const float4*)&Bs[kk][tx * 8 + 4];
            float a[8] = {a0.x,a0.y,a0.z,a0.w,a1.x,a1.y,a1.z,a1.w};
            float b[8] = {b0.x,b0.y,b0.z,b0.w,b1.x,b1.y,b1.z,b1.w};
#pragma unroll
            for (int i = 0; i < 8; ++i)
#pragma unroll
                for (int j = 0; j < 8; ++j)
                    acc[i][j] = fmaf(a[i], b[j], acc[i][j]);
        }
        __syncthreads();
    }
    float4 bias0 = make_float4(0.f,0.f,0.f,0.f), bias1 = bias0;
    if (z) {
        bias0 = *(const float4*)&bz[n0 + tx * 8];
        bias1 = *(const float4*)&bz[n0 + tx * 8 + 4];
    }
#pragma unroll
    for (int i = 0; i < 8; ++i) {
        float4 o0 = make_float4(acc[i][0]+bias0.x, acc[i][1]+bias0.y,
                                acc[i][2]+bias0.z, acc[i][3]+bias0.w);
        float4 o1 = make_float4(acc[i][4]+bias1.x, acc[i][5]+bias1.y,
                                acc[i][6]+bias1.z, acc[i][7]+bias1.w);
        *(float4*)&OUT[(size_t)(m0 + ty * 8 + i) * NHH + n0 + tx * 8] = o0;
        *(float4*)&OUT[(size_t)(m0 + ty * 8 + i) * NHH + n0 + tx * 8 + 4] = o1;
    }
}

// ---------------------------------------------------------------------------
// Recurrent scan — UNCHANGED from round 6 (tied-best, 1.70us/round).
// Session conclusion: this is a latency floor, not a code artifact.
// Evidence matrix (k_recur µs): r0 agent/agent 1745 | r1 2-step pair 2354 |
// r2 128WGx512 2430 | r3 sys-store+fusion 2068 | r4 padded lines 1984 |
// r5 span-2 validate-at-use 2285 | r6 sys/sys 1742 (== r0 bit-identical
// counters -> agent scope already coheres at the shared point; no stale-L2
// window). Round = serial chain {matvec ∥ gather -> reduce -> barrier ->
// gates -> publish -> validate -> Hs -> barrier} + cross-XCD visibility +
// 256-WG straggler sync. HBM 1%, VALU 16%, 0 bank conflicts: pure latency.
// ---------------------------------------------------------------------------
__global__ __launch_bounds__(256, 1) void k_recur(
    const float* __restrict__ XH, const float* __restrict__ XZ,
    const float* __restrict__ Uh, const float* __restrict__ Uz,
    const float* __restrict__ zt0, const float* __restrict__ ht0,
    const float* __restrict__ hp0,
    unsigned long long* __restrict__ Hbuf) {
    __shared__ float Hs[NHH];
    __shared__ float dot_s[16];
    const int tid  = threadIdx.x;
    const int wave = tid >> 6, lane = tid & 63;
    const int base8 = blockIdx.x * 8;

    // load this wave's 4 U rows into registers
    const float* __restrict__ Um = (wave < 2) ? Uz : Uh;
    const int r0 = base8 + (wave & 1) * 4;
    float u[4][32];
#pragma unroll
    for (int r = 0; r < 4; ++r) {
        const float* __restrict__ row = Um + (size_t)(r0 + r) * NHH;
#pragma unroll
        for (int c = 0; c < 8; ++c) {
            float4 v = *(const float4*)&row[c * 256 + lane * 4];
            u[r][c*4+0] = v.x; u[r][c*4+1] = v.y; u[r][c*4+2] = v.z; u[r][c*4+3] = v.w;
        }
    }
    // Hs = P_0 = hprev0 (plain input, no tags needed for epoch 0)
#pragma unroll
    for (int k = 0; k < 8; ++k) Hs[k * 256 + tid] = hp0[k * 256 + tid];

    // own P_1 from initial gates; publish epoch 1
    float p_cur = 0.f;
    if (tid < 8) {
        float z0 = zt0[base8 + tid], g0 = ht0[base8 + tid], p0 = hp0[base8 + tid];
        p_cur = (1.0f - z0) * p0 + z0 * g0;
        unsigned long long pr = (1ull << 32) | (unsigned long long)__float_as_uint(p_cur);
        __hip_atomic_store(&Hbuf[(size_t)1 * NHH + base8 + tid], pr,
                           __ATOMIC_RELAXED, __HIP_MEMORY_SCOPE_SYSTEM);
    }
    __syncthreads();

    for (int t = 1; t < TT; ++t) {
        // (i) issue loads for epoch t; results not touched until (iv)
        const unsigned long long* __restrict__ src = Hbuf + (size_t)(t & 3) * NHH;
        unsigned long long pv[8];
#pragma unroll
        for (int k = 0; k < 8; ++k)
            pv[k] = __hip_atomic_load(&src[k * 256 + tid], __ATOMIC_RELAXED, __HIP_MEMORY_SCOPE_SYSTEM);
        float xzv = 0.f, xhv = 0.f;
        if (tid < 8) {
            xzv = XZ[(size_t)(t - 1) * NHH + base8 + tid];
            xhv = XH[(size_t)(t - 1) * NHH + base8 + tid];
        }
        // (ii) matvec: U @ P_{t-1} from LDS, 4 rows/wave, U in registers
        float a0 = 0.f, a1 = 0.f, a2 = 0.f, a3 = 0.f;
#pragma unroll
        for (int c = 0; c < 8; ++c) {
            float4 h4 = *(const float4*)&Hs[c * 256 + lane * 4];
            a0 = fmaf(u[0][c*4+0], h4.x, fmaf(u[0][c*4+1], h4.y, fmaf(u[0][c*4+2], h4.z, fmaf(u[0][c*4+3], h4.w, a0))));
            a1 = fmaf(u[1][c*4+0], h4.x, fmaf(u[1][c*4+1], h4.y, fmaf(u[1][c*4+2], h4.z, fmaf(u[1][c*4+3], h4.w, a1))));
            a2 = fmaf(u[2][c*4+0], h4.x, fmaf(u[2][c*4+1], h4.y, fmaf(u[2][c*4+2], h4.z, fmaf(u[2][c*4+3], h4.w, a2))));
            a3 = fmaf(u[3][c*4+0], h4.x, fmaf(u[3][c*4+1], h4.y, fmaf(u[3][c*4+2], h4.z, fmaf(u[3][c*4+3], h4.w, a3))));
        }
#pragma unroll
        for (int off = 32; off > 0; off >>= 1) {
            a0 += __shfl_xor(a0, off);
            a1 += __shfl_xor(a1, off);
            a2 += __shfl_xor(a2, off);
            a3 += __shfl_xor(a3, off);
        }
        if (lane == 0) {
            int di = ((wave & 1) * 4) + ((wave >> 1) * 8); // Uz -> 0..7, Uh -> 8..15
            dot_s[di + 0] = a0; dot_s[di + 1] = a1; dot_s[di + 2] = a2; dot_s[di + 3] = a3;
        }
        __syncthreads();
        // (iii) gates from P_{t-1} dots; P_{t+1} = (1-z)*P_t + z*g; publish
        if (tid < 8) {
            float z = 1.0f / (1.0f + expf(-(xzv + dot_s[tid])));
            float g = tanhf(xhv + dot_s[8 + tid]);
            float pn = (1.0f - z) * p_cur + z * g;
            p_cur = pn;
            unsigned long long pr = ((unsigned long long)(unsigned)(t + 1) << 32)
                                  | (unsigned long long)__float_as_uint(pn);
            __hip_atomic_store(&Hbuf[(size_t)((t + 1) & 3) * NHH + base8 + tid], pr,
                               __ATOMIC_RELAXED, __HIP_MEMORY_SCOPE_SYSTEM);
        }
        // (iv) validate epoch-t tags; batched parallel retry of stale ones
        for (;;) {
            unsigned stale = 0;
#pragma unroll
            for (int k = 0; k < 8; ++k)
                if ((unsigned)(pv[k] >> 32) != (unsigned)t) stale |= (1u << k);
            if (!stale) break;
#pragma unroll
            for (int k = 0; k < 8; ++k)
                if (stale & (1u << k))
                    pv[k] = __hip_atomic_load(&src[k * 256 + tid], __ATOMIC_RELAXED, __HIP_MEMORY_SCOPE_SYSTEM);
        }
#pragma unroll
        for (int k = 0; k < 8; ++k) Hs[k * 256 + tid] = __uint_as_float((unsigned)pv[k]);
        __syncthreads();
    }
}

// ---------------------------------------------------------------------------
// logits[r] = Wout[r,:] . P_1024   (epoch 1024 -> slot 0, value in low bits)
// ---------------------------------------------------------------------------
__global__ __launch_bounds__(256) void k_logits(const unsigned long long* __restrict__ Hbuf,
                                                const float* __restrict__ Wout,
                                                float* __restrict__ lg) {
    __shared__ float Hs[NHH];
    const int tid = threadIdx.x;
    for (int k = tid; k < NHH; k += 256) Hs[k] = __uint_as_float((unsigned)Hbuf[k]);
    __syncthreads();
    const int wave = tid >> 6, lane = tid & 63;
    const int row = blockIdx.x * 4 + wave;
    float a = 0.f;
#pragma unroll
    for (int c = 0; c < 8; ++c) {
        float4 w = *(const float4*)&Wout[(size_t)row * NHH + c * 256 + lane * 4];
        float4 h = *(const float4*)&Hs[c * 256 + lane * 4];
        a = fmaf(w.x, h.x, fmaf(w.y, h.y, fmaf(w.z, h.z, fmaf(w.w, h.w, a))));
    }
#pragma unroll
    for (int off = 32; off > 0; off >>= 1) a += __shfl_xor(a, off);
    if (lane == 0) lg[row] = a;
}

// ---------------------------------------------------------------------------
// softmax over 1000 logits, single block
// ---------------------------------------------------------------------------
__global__ __launch_bounds__(1024) void k_softmax(const float* __restrict__ lg,
                                                  float* __restrict__ out) {
    const int i = threadIdx.x;
    __shared__ float red[16];
    __shared__ float bc[2];
    float v = (i < CC) ? lg[i] : -3.0e38f;
    float m = v;
#pragma unroll
    for (int off = 32; off > 0; off >>= 1) m = fmaxf(m, __shfl_xor(m, off));
    if ((i & 63) == 0) red[i >> 6] = m;
    __syncthreads();
    if (i == 0) { float mm = red[0]; for (int k = 1; k < 16; ++k) mm = fmaxf(mm, red[k]); bc[0] = mm; }
    __syncthreads();
    float e = (i < CC) ? expf(v - bc[0]) : 0.f;
    float s = e;
#pragma unroll
    for (int off = 32; off > 0; off >>= 1) s += __shfl_xor(s, off);
    if ((i & 63) == 0) red[i >> 6] = s;
    __syncthreads();
    if (i == 0) { float ss = 0.f; for (int k = 0; k < 16; ++k) ss += red[k]; bc[1] = ss; }
    __syncthreads();
    if (i < CC) out[i] = e / bc[1];
}

extern "C" void kernel_launch(void* const* d_in, const int* in_sizes, int n_in,
                              void* d_out, int out_size, void* d_ws, size_t ws_size,
                              hipStream_t stream) {
    const float* x    = (const float*)d_in[0];
    const float* Wh   = (const float*)d_in[1];
    const float* Wz   = (const float*)d_in[2];
    // d_in[3] = Wr  (dead code in reference)
    const float* Uh   = (const float*)d_in[4];
    const float* Uz   = (const float*)d_in[5];
    const float* bz   = (const float*)d_in[6];
    // d_in[7] = Ur, d_in[8] = br (dead code)
    const float* Wout = (const float*)d_in[9];
    // d_in[10] = h0 (overwritten before first use since T>=1)
    const float* zt0  = (const float*)d_in[11];
    const float* ht0  = (const float*)d_in[12];
    const float* hp0  = (const float*)d_in[13];
    float* out = (float*)d_out;

    float* XH = (float*)d_ws;                                   // T*NH f32
    float* XZ = XH + (size_t)TT * NHH;                          // T*NH f32
    unsigned long long* Hbuf = (unsigned long long*)(XZ + (size_t)TT * NHH); // 4*NH u64
    float* lg = (float*)(Hbuf + 4 * NHH);                       // CC f32

    k_gemm<<<dim3(NHH / 128, TT / 128, 2), dim3(256), 0, stream>>>(x, Wh, Wz, bz, XH, XZ);
    k_recur<<<dim3(256), dim3(256), 0, stream>>>(XH, XZ, Uh, Uz, zt0, ht0, hp0, Hbuf);
    k_logits<<<dim3(250), dim3(256), 0, stream>>>(Hbuf, Wout, lg);
    k_softmax<<<dim3(1), dim3(1024), 0, stream>>>(lg, out);
}